// Round 10
// baseline (104.982 us; speedup 1.0000x reference)
//
#include <hip/hip_runtime.h>
#include <math.h>

// Problem constants (from reference setup_inputs)
#define B   16
#define NH  1024
#define NO  2048
#define DQ  24

#define ALPHA_FOCAL 0.25f
#define MARGIN_PEN  0.005f
#define RADIUS_REP  0.015f
#define R2REP       (RADIUS_REP * RADIUS_REP)

// ws layout:
//   float [0..16) scalar slots:
//     0,1: hand cd dir1/dir2   2,3: obj cd dir1/dir2 (weighted)
//     4: repulsion shifted sum S=sum min(d,R) incl diag (weighted)
//     5: penetration (weighted)  6: focal  7: qpos  8: pose (weighted)
//     9: valid   15: combine ticket counter (uint)
//   uint [16..16+131072): per-row ~bits(min d2) via atomicMax (init 0).
//   Slot mapping inside a 1024-row set: slot = (2kk+e)*64 + l (consistent
//   bijection; combine just sums the segment).
//     hand d1 [0,16384) hand d2 [16384,32768)
//     obj d1 [32768,65536) obj d2 [65536,98304) pen [98304,131072)
#define WS_SCAL    16
#define ROWS_TOTAL 131072

typedef float v2f __attribute__((ext_vector_type(2)));
typedef float v4f __attribute__((ext_vector_type(4)));

__device__ inline float wsqrt(float x) { return __builtin_amdgcn_sqrtf(x); }

__device__ inline float block_reduce_sum(float v, float* red) {
    #pragma unroll
    for (int off = 32; off > 0; off >>= 1) v += __shfl_down(v, off, 64);
    int lane = threadIdx.x & 63;
    int wid  = threadIdx.x >> 6;
    if (lane == 0) red[wid] = v;
    __syncthreads();
    float s = 0.f;
    if (threadIdx.x == 0) s = red[0] + red[1] + red[2] + red[3];
    __syncthreads();
    return s;   // valid in thread 0 only
}

// 1024 uniform blocks. Block = (segment, b, pc[, dir]); its 4 waves are 4
// consecutive jc-chunks (jc = jg*4 + w) over the SAME 1024-row set.
// Per-wave mins merge in LDS; ONE lane-consecutive atomicMax set per block.
// jc-group (jg) is the SLOW index digit: blocks sharing a row-set satisfy
// k ≡ c (mod 32) -> same XCD under round-robin dispatch -> atomics L2-local.
//  [  0,256): obj cd dir0/1: k = dir*256 + jg*32 + (b*2+pc), jg<8
//  [256,512): obj cd dir1
//  [512,768): repulsion:     k-512 = jg*32 + (b*2+pc), jg<8 (sum only)
//  [768,896): hand cd:       k-768 = jg*32 + dir*16 + b, jg<4
//  [896,1024): penetration:  k-896 = jg*32 + (b*2+pc), jg<4
__global__ __launch_bounds__(256, 4) void pairwise_kernel(
    const float* __restrict__ pred_hand, const float* __restrict__ pred_obj,
    const float* __restrict__ gt_hand,   const float* __restrict__ gt_obj,
    const float* __restrict__ has_contact, float* __restrict__ ws)
{
    __shared__ v4f   qs[256];       // 4 KiB: 4 waves x 64 cols {-2x,-2y,-2z,|q|^2}
    __shared__ float mbuf[4][1024]; // 16 KiB: per-wave row mins (pn included)

    const int tid = threadIdx.x;
    const int w   = tid >> 6;
    const int l   = tid & 63;
    const int k   = blockIdx.x;

    unsigned* rowmin = (unsigned*)(ws + WS_SCAL);
    const float* Pb; const float* Qb;
    int b, rowbase = 0, rep = 0;

    if (k < 512) {                          // obj chamfer dir0/dir1
        int dir = k >> 8, t = k & 255;
        int jg = t >> 5, c = t & 31;
        b = c >> 1; int pc = c & 1, jc = (jg << 2) | w;
        Pb = (dir ? gt_obj : pred_obj) + b*NO*3 + pc*1024*3;
        Qb = (dir ? pred_obj : gt_obj) + b*NO*3 + jc*64*3;
        rowbase = 32768 + dir*32768 + b*2048 + pc*1024;
    } else if (k < 768) {                   // repulsion
        int t = k - 512;
        int jg = t >> 5, c = t & 31;
        b = c >> 1; int pc = c & 1, jc = (jg << 2) | w;
        Pb = pred_obj + b*NO*3 + pc*1024*3;
        Qb = pred_obj + b*NO*3 + jc*64*3;
        rep = 1;
    } else if (k < 896) {                   // hand chamfer
        int t = k - 768;
        int jg = t >> 5, c = t & 31;
        int dir = c >> 4; b = c & 15; int jc = (jg << 2) | w;
        Pb = (dir ? gt_hand : pred_hand) + b*NH*3;
        Qb = (dir ? pred_hand : gt_hand) + b*NH*3 + jc*64*3;
        rowbase = dir*16384 + b*1024;
    } else {                                // penetration
        int t = k - 896;
        int jg = t >> 5, c = t & 31;
        b = c >> 1; int pc = c & 1, jc = (jg << 2) | w;
        Pb = pred_obj  + b*NO*3 + pc*1024*3;
        Qb = pred_hand + b*NH*3 + jc*64*3;
        rowbase = 98304 + b*2048 + pc*1024;
    }

    // This lane's 16 contiguous P rows: 12 x dwordx4 (48 floats).
    // All 4 waves read the SAME P set -> L1 hits after the first wave.
    v4f f4[12];
    const v4f* pv = (const v4f*)(Pb + l*48);
    #pragma unroll
    for (int i = 0; i < 12; ++i) f4[i] = pv[i];
    const float* f = (const float*)f4;

    // Stage this wave's 64 Q cols into its private LDS region
    {
        const float* qp = Qb + l*3;
        float x = qp[0], y = qp[1], z = qp[2];
        qs[(w << 6) | l] = (v4f){-2.f*x, -2.f*y, -2.f*z, fmaf(x, x, fmaf(y, y, z*z))};
    }
    // Wave reads only its own qs region (ds ordering via lgkmcnt).

    // 8 row-pairs (rows 2kk, 2kk+1 of this lane's 16)
    v2f px2[8], py2[8], pz2[8];
    #pragma unroll
    for (int kk = 0; kk < 8; ++kk) {
        px2[kk] = (v2f){f[6*kk+0], f[6*kk+3]};
        py2[kk] = (v2f){f[6*kk+1], f[6*kk+4]};
        pz2[kk] = (v2f){f[6*kk+2], f[6*kk+5]};
    }

    const v4f* qw = qs + (w << 6);

    if (rep) {
        v2f pn2[8];
        #pragma unroll
        for (int kk = 0; kk < 8; ++kk)
            pn2[kk] = __builtin_elementwise_fma(px2[kk], px2[kk],
                      __builtin_elementwise_fma(py2[kk], py2[kk], pz2[kk]*pz2[kk]));
        v2f sacc = (v2f){0.f, 0.f};
        const v2f vR = (v2f){RADIUS_REP, RADIUS_REP};
        auto rstep = [&](v4f Q) {
            v2f bx = __builtin_shufflevector(Q, Q, 0, 0);
            v2f by = __builtin_shufflevector(Q, Q, 1, 1);
            v2f bz = __builtin_shufflevector(Q, Q, 2, 2);
            v2f bw = __builtin_shufflevector(Q, Q, 3, 3);
            #pragma unroll
            for (int kk = 0; kk < 8; ++kk) {
                v2f t = __builtin_elementwise_fma(bz, pz2[kk], bw);
                t     = __builtin_elementwise_fma(by, py2[kk], t);
                t     = __builtin_elementwise_fma(bx, px2[kk], t);
                v2f d2 = t + pn2[kk];
                if (__any(fminf(d2.x, d2.y) < R2REP)) {
                    // min(d,R) exactly (diag d2~0 -> ~1e-6, fixed in finalize)
                    v2f dd;
                    dd.x = wsqrt(__builtin_amdgcn_fmed3f(d2.x, 1e-12f, R2REP));
                    dd.y = wsqrt(__builtin_amdgcn_fmed3f(d2.y, 1e-12f, R2REP));
                    sacc += dd;
                } else {
                    sacc += vR;     // min(d,R) = R for both elements
                }
            }
        };
        v4f Q0 = qw[0], Q1 = qw[1], Q2 = qw[2], Q3 = qw[3];
        for (int j = 0; j < 60; j += 4) {
            rstep(Q0); Q0 = qw[j+4];
            rstep(Q1); Q1 = qw[j+5];
            rstep(Q2); Q2 = qw[j+6];
            rstep(Q3); Q3 = qw[j+7];
        }
        rstep(Q0); rstep(Q1); rstep(Q2); rstep(Q3);

        float s = sacc.x + sacc.y;
        #pragma unroll
        for (int off = 32; off > 0; off >>= 1) s += __shfl_down(s, off, 64);
        if (l == 0) atomicAdd(&ws[4], s * has_contact[b]);
    } else {
        v2f m2[8];
        #pragma unroll
        for (int kk = 0; kk < 8; ++kk) m2[kk] = (v2f){1e30f, 1e30f};
        auto cstep = [&](v4f Q) {
            v2f bx = __builtin_shufflevector(Q, Q, 0, 0);
            v2f by = __builtin_shufflevector(Q, Q, 1, 1);
            v2f bz = __builtin_shufflevector(Q, Q, 2, 2);
            v2f bw = __builtin_shufflevector(Q, Q, 3, 3);
            #pragma unroll
            for (int kk = 0; kk < 8; ++kk) {
                v2f t = __builtin_elementwise_fma(bz, pz2[kk], bw);
                t     = __builtin_elementwise_fma(by, py2[kk], t);
                t     = __builtin_elementwise_fma(bx, px2[kk], t);
                m2[kk] = __builtin_elementwise_min(m2[kk], t);
            }
        };
        v4f Q0 = qw[0], Q1 = qw[1], Q2 = qw[2], Q3 = qw[3];
        for (int j = 0; j < 60; j += 4) {
            cstep(Q0); Q0 = qw[j+4];
            cstep(Q1); Q1 = qw[j+5];
            cstep(Q2); Q2 = qw[j+6];
            cstep(Q3); Q3 = qw[j+7];
        }
        cstep(Q0); cstep(Q1); cstep(Q2); cstep(Q3);

        // Per-wave mins (pn folded in: exact for min-merge) -> LDS
        #pragma unroll
        for (int kk = 0; kk < 8; ++kk) {
            #pragma unroll
            for (int e = 0; e < 2; ++e) {
                float x = px2[kk][e], y = py2[kk][e], z = pz2[kk][e];
                float pn = fmaf(x, x, fmaf(y, y, z*z));
                mbuf[w][((2*kk + e) << 6) + l] = m2[kk][e] + pn;
            }
        }
        __syncthreads();
        // Merge 4 waves' mins; one lane-consecutive atomic set per block
        #pragma unroll
        for (int q = 0; q < 4; ++q) {
            int s = (q << 8) + tid;
            float mv = fminf(fminf(mbuf[0][s], mbuf[1][s]),
                             fminf(mbuf[2][s], mbuf[3][s]));
            unsigned c = ~__float_as_uint(fmaxf(mv, 1e-12f));
            atomicMax(&rowmin[rowbase + s], c);
        }
    }
}

// 131 blocks: [0,128) rowmin reduction (1024 rows each, uint4/thread),
// 128 focal, 129 qpos, 130 pose+valid. Last arrival (ticket) finalizes.
__global__ __launch_bounds__(256) void combine_kernel(
    const float* __restrict__ has_contact,
    const float* __restrict__ logits,    const float* __restrict__ gt_contact,
    const float* __restrict__ pred_qpos, const float* __restrict__ gt_qpos,
    const float* __restrict__ pred_pose, const float* __restrict__ gt_pose,
    float* __restrict__ ws, float* __restrict__ out)
{
    __shared__ float red[4];
    const unsigned* rowmin = (const unsigned*)(ws + WS_SCAL);
    int blk = blockIdx.x;
    int tid = threadIdx.x;

    if (blk < 128) {
        int slot, pen = 0;
        float w = 1.f;
        if      (blk < 16)  { slot = 0; }
        else if (blk < 32)  { slot = 1; }
        else if (blk < 64)  { slot = 2; w = has_contact[(blk - 32) >> 1]; }
        else if (blk < 96)  { slot = 3; w = has_contact[(blk - 64) >> 1]; }
        else                { slot = 5; w = has_contact[(blk - 96) >> 1]; pen = 1; }
        const uint4* p = (const uint4*)(rowmin + blk*1024);
        uint4 v = p[tid];
        float s = 0.f;
        #pragma unroll
        for (int e = 0; e < 4; ++e) {
            unsigned u = (&v.x)[e];
            float d = wsqrt(__uint_as_float(~u));
            s += pen ? fmaxf(MARGIN_PEN - d, 0.f) : d;
        }
        float bs = block_reduce_sum(s, red);
        if (tid == 0) atomicAdd(&ws[slot], bs * w);
    } else if (blk == 128) {
        float fsum = 0.f;
        for (int i = tid; i < B*NH; i += 256) {
            float l = logits[i];
            float y = gt_contact[i];
            float bce = fmaxf(l, 0.f) - l*y + log1pf(expf(-fabsf(l)));
            float pt  = expf(-bce);
            float om  = 1.f - pt;
            fsum += ALPHA_FOCAL * om * om * bce;
        }
        float fT = block_reduce_sum(fsum, red);
        if (tid == 0) atomicAdd(&ws[6], fT);
    } else if (blk == 129) {
        float qsum = 0.f;
        for (int i = tid; i < B*DQ; i += 256) {
            float d = pred_qpos[i] - gt_qpos[i];
            qsum += d*d;
        }
        float qT = block_reduce_sum(qsum, red);
        if (tid == 0) atomicAdd(&ws[7], qT);
    } else {
        float psum = 0.f, vsum = 0.f;
        if (tid < B) {
            const float* pp = pred_pose + tid*7;
            const float* gp = gt_pose   + tid*7;
            float lt = (fabsf(pp[0]-gp[0]) + fabsf(pp[1]-gp[1]) + fabsf(pp[2]-gp[2])) * (1.f/3.f);
            float npn = wsqrt(pp[3]*pp[3] + pp[4]*pp[4] + pp[5]*pp[5] + pp[6]*pp[6]);
            float ngn = wsqrt(gp[3]*gp[3] + gp[4]*gp[4] + gp[5]*gp[5] + gp[6]*gp[6]);
            float dot = (pp[3]*gp[3] + pp[4]*gp[4] + pp[5]*gp[5] + pp[6]*gp[6]) / (npn * ngn);
            float lr = 1.f - fabsf(dot);
            psum = (lt + 0.1f*lr) * has_contact[tid];
            vsum = has_contact[tid];
        }
        float pT = block_reduce_sum(psum, red);
        float vT = block_reduce_sum(vsum, red);
        if (tid == 0) { atomicAdd(&ws[8], pT); atomicAdd(&ws[9], vT); }
    }

    if (tid == 0) {
        __threadfence();
        unsigned* cnt = (unsigned*)(ws + 15);
        unsigned old = atomicAdd(cnt, 1u);
        if (old == 130u) {                      // last of 131 blocks finalizes
            __threadfence();
            float s0 = atomicAdd(&ws[0], 0.f), s1 = atomicAdd(&ws[1], 0.f);
            float s2 = atomicAdd(&ws[2], 0.f), s3 = atomicAdd(&ws[3], 0.f);
            float s4 = atomicAdd(&ws[4], 0.f), s5 = atomicAdd(&ws[5], 0.f);
            float s6 = atomicAdd(&ws[6], 0.f), s7 = atomicAdd(&ws[7], 0.f);
            float s8 = atomicAdd(&ws[8], 0.f), s9 = atomicAdd(&ws[9], 0.f);
            double vT    = s9;
            double valid = vT + 1e-6;
            double NOd   = (double)NO;
            // repulsion: sum relu(R-d) = hc-weighted (NO^2*R - S) minus diagonal
            double repw  = vT*NOd*NOd*(double)RADIUS_REP - (double)s4;
            double repx  = repw - vT*NOd*((double)RADIUS_REP - 1e-6);
            double loss_cd_hand = ((double)s0 + (double)s1) / (double)(B*NH);
            double loss_cd_obj  = ((double)s2 + (double)s3) / (NOd * valid);
            double loss_rep     = repx / (NOd * NOd * valid);
            double loss_pen     = (double)s5 / (NOd * valid);
            double loss_pose    = (double)s8 / valid;
            double loss_qpos    = (double)s7 / (double)(B*DQ);
            double loss_contact = (double)s6 / (double)(B*NH);
            double total = 5.0*loss_cd_hand + 5.0*loss_cd_obj + 2.0*loss_pose
                         + 1.0*loss_qpos + 2.0*loss_contact
                         + 0.5*loss_rep + 0.5*loss_pen;
            out[0] = (float)total;
        }
    }
}

extern "C" void kernel_launch(void* const* d_in, const int* in_sizes, int n_in,
                              void* d_out, int out_size, void* d_ws, size_t ws_size,
                              hipStream_t stream) {
    const float* pred_hand   = (const float*)d_in[0];
    const float* pred_obj    = (const float*)d_in[1];
    const float* pred_pose   = (const float*)d_in[2];
    const float* pred_qpos   = (const float*)d_in[3];
    const float* logits      = (const float*)d_in[4];
    const float* gt_hand     = (const float*)d_in[5];
    const float* gt_obj      = (const float*)d_in[6];
    const float* gt_pose     = (const float*)d_in[7];
    const float* gt_qpos     = (const float*)d_in[8];
    const float* gt_contact  = (const float*)d_in[9];
    const float* has_contact = (const float*)d_in[10];

    float* ws = (float*)d_ws;

    // single init: scalars+ticket <- 0, rowmin (complement-coded) <- 0
    hipMemsetAsync(ws, 0, (WS_SCAL + ROWS_TOTAL) * sizeof(float), stream);

    pairwise_kernel<<<1024, 256, 0, stream>>>(pred_hand, pred_obj, gt_hand, gt_obj,
                                              has_contact, ws);
    combine_kernel<<<131, 256, 0, stream>>>(has_contact, logits, gt_contact,
                                            pred_qpos, gt_qpos, pred_pose, gt_pose,
                                            ws, (float*)d_out);
}

// Round 11
// 77.104 us; speedup vs baseline: 1.3616x; 1.3616x over previous
//
#include <hip/hip_runtime.h>
#include <math.h>

// Problem constants (from reference setup_inputs)
#define B   16
#define NH  1024
#define NO  2048
#define DQ  24

#define ALPHA_FOCAL 0.25f
#define MARGIN_PEN  0.005f
#define RADIUS_REP  0.015f
#define R2REP       (RADIUS_REP * RADIUS_REP)

// ws layout (floats, 64 B total — the ONLY global scratch):
//   0,1: hand cd dir0/dir1   2,3: obj cd dir0/dir1 (hc-weighted)
//   4: repulsion shifted sum S = sum min(d,R) incl diag (hc-weighted)
//   5: penetration (hc-weighted)  6: focal  7: qpos  8: pose (hc-weighted)
//   9: valid   15: ticket counter (uint)
#define WS_SCAL 16

typedef float v2f __attribute__((ext_vector_type(2)));
typedef float v4f __attribute__((ext_vector_type(4)));

__device__ inline float wsqrt(float x) { return __builtin_amdgcn_sqrtf(x); }

__device__ inline float block_reduce_sum(float v, float* red) {
    #pragma unroll
    for (int off = 32; off > 0; off >>= 1) v += __shfl_down(v, off, 64);
    int lane = threadIdx.x & 63;
    int wid  = threadIdx.x >> 6;
    if (lane == 0) red[wid] = v;
    __syncthreads();
    float s = 0.f;
    if (threadIdx.x == 0) s = red[0] + red[1] + red[2] + red[3];
    __syncthreads();
    return s;   // valid in thread 0 only
}

// Chamfer/penetration block: ROWS = 128*NRP rows (2*NRP rows/lane), ALL NQ
// cols. 4 waves split cols (NC chunks of 64 each, col = c*256 + w*64 + l).
// Per-wave running min in regs; LDS merge; one atomicAdd per block.
template<int NRP, int NC, bool PEN>
__device__ __forceinline__ void chamfer_block(
    const float* __restrict__ Pb, const float* __restrict__ Qb,
    int slot, float weight,
    v4f (*qsb)[4][64], float (*mbuf)[512], float* red, float* ws)
{
    const int tid = threadIdx.x;
    const int w   = tid >> 6;
    const int l   = tid & 63;

    // P rows: 2*NRP contiguous rows/lane = 6*NRP floats, vectorized
    v4f f4[(3*NRP)/2];
    const v4f* pv = (const v4f*)(Pb + l*(6*NRP));
    #pragma unroll
    for (int i = 0; i < (3*NRP)/2; ++i) f4[i] = pv[i];
    const float* f = (const float*)f4;

    v2f px2[NRP], py2[NRP], pz2[NRP], m2[NRP];
    #pragma unroll
    for (int rp = 0; rp < NRP; ++rp) {
        px2[rp] = (v2f){f[6*rp+0], f[6*rp+3]};
        py2[rp] = (v2f){f[6*rp+1], f[6*rp+4]};
        pz2[rp] = (v2f){f[6*rp+2], f[6*rp+5]};
        m2[rp]  = (v2f){1e30f, 1e30f};
    }

    auto cstep = [&](v4f Q) {
        v2f bx = __builtin_shufflevector(Q, Q, 0, 0);
        v2f by = __builtin_shufflevector(Q, Q, 1, 1);
        v2f bz = __builtin_shufflevector(Q, Q, 2, 2);
        v2f bw = __builtin_shufflevector(Q, Q, 3, 3);
        #pragma unroll
        for (int rp = 0; rp < NRP; ++rp) {
            v2f t = __builtin_elementwise_fma(bz, pz2[rp], bw);
            t     = __builtin_elementwise_fma(by, py2[rp], t);
            t     = __builtin_elementwise_fma(bx, px2[rp], t);
            m2[rp] = __builtin_elementwise_min(m2[rp], t);
        }
    };

    // chunk 0 Q point
    const float* qp0 = Qb + (w*64 + l)*3;
    float qx = qp0[0], qy = qp0[1], qz = qp0[2];
    int p = 0;
    #pragma unroll 1
    for (int c = 0; c < NC; ++c) {
        qsb[p][w][l] = (v4f){-2.f*qx, -2.f*qy, -2.f*qz,
                             fmaf(qx, qx, fmaf(qy, qy, qz*qz))};
        if (c + 1 < NC) {
            const float* qp = Qb + ((c+1)*256 + w*64 + l)*3;
            qx = qp[0]; qy = qp[1]; qz = qp[2];
        }
        const v4f* qw_ = qsb[p][w];
        v4f Q0 = qw_[0], Q1 = qw_[1], Q2 = qw_[2], Q3 = qw_[3];
        for (int j = 0; j < 60; j += 4) {
            cstep(Q0); Q0 = qw_[j+4];
            cstep(Q1); Q1 = qw_[j+5];
            cstep(Q2); Q2 = qw_[j+6];
            cstep(Q3); Q3 = qw_[j+7];
        }
        cstep(Q0); cstep(Q1); cstep(Q2); cstep(Q3);
        p ^= 1;
    }

    // per-wave mins (pn folded: exact for min-merge) -> LDS
    #pragma unroll
    for (int rp = 0; rp < NRP; ++rp) {
        #pragma unroll
        for (int e = 0; e < 2; ++e) {
            float x = px2[rp][e], y = py2[rp][e], z = pz2[rp][e];
            float pn = fmaf(x, x, fmaf(y, y, z*z));
            mbuf[w][l*(2*NRP) + 2*rp + e] = m2[rp][e] + pn;
        }
    }
    __syncthreads();

    const int ROWS = 128 * NRP;
    float s = 0.f;
    #pragma unroll
    for (int r = tid; r < ROWS; r += 256) {
        float mv = fminf(fminf(mbuf[0][r], mbuf[1][r]),
                         fminf(mbuf[2][r], mbuf[3][r]));
        float d = wsqrt(fmaxf(mv, 1e-12f));
        s += PEN ? fmaxf(MARGIN_PEN - d, 0.f) : d;
    }
    float bs = block_reduce_sum(s, red);
    if (tid == 0) atomicAdd(&ws[slot], bs * weight);
}

// Repulsion block: 256 rows x 2048 cols; sum of min(d,R) (diag included,
// fixed analytically in finalize). One atomicAdd per block.
__device__ __forceinline__ void rep_block(
    const float* __restrict__ Pb, const float* __restrict__ Qb,
    float weight, v4f (*qsb)[4][64], float* red, float* ws)
{
    const int tid = threadIdx.x;
    const int w   = tid >> 6;
    const int l   = tid & 63;

    v4f f4[3];
    const v4f* pv = (const v4f*)(Pb + l*12);
    #pragma unroll
    for (int i = 0; i < 3; ++i) f4[i] = pv[i];
    const float* f = (const float*)f4;

    v2f px2[2], py2[2], pz2[2], pn2[2];
    #pragma unroll
    for (int rp = 0; rp < 2; ++rp) {
        px2[rp] = (v2f){f[6*rp+0], f[6*rp+3]};
        py2[rp] = (v2f){f[6*rp+1], f[6*rp+4]};
        pz2[rp] = (v2f){f[6*rp+2], f[6*rp+5]};
        pn2[rp] = __builtin_elementwise_fma(px2[rp], px2[rp],
                  __builtin_elementwise_fma(py2[rp], py2[rp], pz2[rp]*pz2[rp]));
    }

    v2f sacc = (v2f){0.f, 0.f};
    const v2f vR = (v2f){RADIUS_REP, RADIUS_REP};
    auto rstep = [&](v4f Q) {
        v2f bx = __builtin_shufflevector(Q, Q, 0, 0);
        v2f by = __builtin_shufflevector(Q, Q, 1, 1);
        v2f bz = __builtin_shufflevector(Q, Q, 2, 2);
        v2f bw = __builtin_shufflevector(Q, Q, 3, 3);
        #pragma unroll
        for (int rp = 0; rp < 2; ++rp) {
            v2f t = __builtin_elementwise_fma(bz, pz2[rp], bw);
            t     = __builtin_elementwise_fma(by, py2[rp], t);
            t     = __builtin_elementwise_fma(bx, px2[rp], t);
            v2f d2 = t + pn2[rp];
            if (__any(fminf(d2.x, d2.y) < R2REP)) {
                v2f dd;
                dd.x = wsqrt(__builtin_amdgcn_fmed3f(d2.x, 1e-12f, R2REP));
                dd.y = wsqrt(__builtin_amdgcn_fmed3f(d2.y, 1e-12f, R2REP));
                sacc += dd;
            } else {
                sacc += vR;     // min(d,R) = R for both elements
            }
        }
    };

    const float* qp0 = Qb + (w*64 + l)*3;
    float qx = qp0[0], qy = qp0[1], qz = qp0[2];
    int p = 0;
    #pragma unroll 1
    for (int c = 0; c < 8; ++c) {
        qsb[p][w][l] = (v4f){-2.f*qx, -2.f*qy, -2.f*qz,
                             fmaf(qx, qx, fmaf(qy, qy, qz*qz))};
        if (c + 1 < 8) {
            const float* qp = Qb + ((c+1)*256 + w*64 + l)*3;
            qx = qp[0]; qy = qp[1]; qz = qp[2];
        }
        const v4f* qw_ = qsb[p][w];
        v4f Q0 = qw_[0], Q1 = qw_[1], Q2 = qw_[2], Q3 = qw_[3];
        for (int j = 0; j < 60; j += 4) {
            rstep(Q0); Q0 = qw_[j+4];
            rstep(Q1); Q1 = qw_[j+5];
            rstep(Q2); Q2 = qw_[j+6];
            rstep(Q3); Q3 = qw_[j+7];
        }
        rstep(Q0); rstep(Q1); rstep(Q2); rstep(Q3);
        p ^= 1;
    }

    float bs = block_reduce_sum(sacc.x + sacc.y, red);
    if (tid == 0) atomicAdd(&ws[4], bs * weight);
}

// 515 blocks, one kernel, one scalar atomic per block:
//  [  0,256): obj cd   dir(2) x b(16) x rs(8): 256 rows x 2048 cols
//  [256,384): repulsion b(16) x rs(8):         256 rows x 2048 cols
//  [384,448): hand cd  dir(2) x b(16) x rs(2): 512 rows x 1024 cols
//  [448,512): pen      b(16) x rs(4):          512 rows x 1024 cols
//  512 focal, 513 qpos, 514 pose+valid. Ticket: last of 515 finalizes out[0].
__global__ __launch_bounds__(256, 4) void loss_kernel(
    const float* __restrict__ pred_hand, const float* __restrict__ pred_obj,
    const float* __restrict__ gt_hand,   const float* __restrict__ gt_obj,
    const float* __restrict__ has_contact,
    const float* __restrict__ logits,    const float* __restrict__ gt_contact,
    const float* __restrict__ pred_qpos, const float* __restrict__ gt_qpos,
    const float* __restrict__ pred_pose, const float* __restrict__ gt_pose,
    float* __restrict__ ws, float* __restrict__ out)
{
    __shared__ v4f   qsb[2][4][64];   // 8 KiB double-buffered Q staging
    __shared__ float mbuf[4][512];    // 8 KiB per-wave min merge
    __shared__ float red[4];

    const int tid = threadIdx.x;
    const int k   = blockIdx.x;

    if (k < 256) {                          // obj chamfer
        int dir = k >> 7, r = k & 127;
        int b = r >> 3, rs = r & 7;
        const float* Pb = (dir ? gt_obj : pred_obj) + b*NO*3 + rs*256*3;
        const float* Qb = (dir ? pred_obj : gt_obj) + b*NO*3;
        chamfer_block<2, 8, false>(Pb, Qb, 2 + dir, has_contact[b],
                                   qsb, mbuf, red, ws);
    } else if (k < 384) {                   // repulsion
        int t = k - 256;
        int b = t >> 3, rs = t & 7;
        const float* Pb = pred_obj + b*NO*3 + rs*256*3;
        const float* Qb = pred_obj + b*NO*3;
        rep_block(Pb, Qb, has_contact[b], qsb, red, ws);
    } else if (k < 448) {                   // hand chamfer
        int t = k - 384;
        int dir = t >> 5, r = t & 31;
        int b = r >> 1, rs = r & 1;
        const float* Pb = (dir ? gt_hand : pred_hand) + b*NH*3 + rs*512*3;
        const float* Qb = (dir ? pred_hand : gt_hand) + b*NH*3;
        chamfer_block<4, 4, false>(Pb, Qb, dir, 1.f, qsb, mbuf, red, ws);
    } else if (k < 512) {                   // penetration
        int t = k - 448;
        int b = t >> 2, rs = t & 3;
        const float* Pb = pred_obj  + b*NO*3 + rs*512*3;
        const float* Qb = pred_hand + b*NH*3;
        chamfer_block<4, 4, true>(Pb, Qb, 5, has_contact[b], qsb, mbuf, red, ws);
    } else if (k == 512) {                  // focal
        float fsum = 0.f;
        for (int i = tid; i < B*NH; i += 256) {
            float l = logits[i];
            float y = gt_contact[i];
            float bce = fmaxf(l, 0.f) - l*y + log1pf(expf(-fabsf(l)));
            float pt  = expf(-bce);
            float om  = 1.f - pt;
            fsum += ALPHA_FOCAL * om * om * bce;
        }
        float fT = block_reduce_sum(fsum, red);
        if (tid == 0) atomicAdd(&ws[6], fT);
    } else if (k == 513) {                  // qpos
        float qsum = 0.f;
        for (int i = tid; i < B*DQ; i += 256) {
            float d = pred_qpos[i] - gt_qpos[i];
            qsum += d*d;
        }
        float qT = block_reduce_sum(qsum, red);
        if (tid == 0) atomicAdd(&ws[7], qT);
    } else {                                // pose + valid
        float psum = 0.f, vsum = 0.f;
        if (tid < B) {
            const float* pp = pred_pose + tid*7;
            const float* gp = gt_pose   + tid*7;
            float lt = (fabsf(pp[0]-gp[0]) + fabsf(pp[1]-gp[1]) + fabsf(pp[2]-gp[2])) * (1.f/3.f);
            float npn = wsqrt(pp[3]*pp[3] + pp[4]*pp[4] + pp[5]*pp[5] + pp[6]*pp[6]);
            float ngn = wsqrt(gp[3]*gp[3] + gp[4]*gp[4] + gp[5]*gp[5] + gp[6]*gp[6]);
            float dot = (pp[3]*gp[3] + pp[4]*gp[4] + pp[5]*gp[5] + pp[6]*gp[6]) / (npn * ngn);
            float lr = 1.f - fabsf(dot);
            psum = (lt + 0.1f*lr) * has_contact[tid];
            vsum = has_contact[tid];
        }
        float pT = block_reduce_sum(psum, red);
        float vT = block_reduce_sum(vsum, red);
        if (tid == 0) { atomicAdd(&ws[8], pT); atomicAdd(&ws[9], vT); }
    }

    if (tid == 0) {
        __threadfence();
        unsigned* cnt = (unsigned*)(ws + 15);
        unsigned old = atomicAdd(cnt, 1u);
        if (old == 514u) {                  // last of 515 blocks finalizes
            __threadfence();
            float s0 = atomicAdd(&ws[0], 0.f), s1 = atomicAdd(&ws[1], 0.f);
            float s2 = atomicAdd(&ws[2], 0.f), s3 = atomicAdd(&ws[3], 0.f);
            float s4 = atomicAdd(&ws[4], 0.f), s5 = atomicAdd(&ws[5], 0.f);
            float s6 = atomicAdd(&ws[6], 0.f), s7 = atomicAdd(&ws[7], 0.f);
            float s8 = atomicAdd(&ws[8], 0.f), s9 = atomicAdd(&ws[9], 0.f);
            double vT    = s9;
            double valid = vT + 1e-6;
            double NOd   = (double)NO;
            // repulsion: sum relu(R-d) = hc-weighted (NO^2*R - S) minus diagonal
            double repw  = vT*NOd*NOd*(double)RADIUS_REP - (double)s4;
            double repx  = repw - vT*NOd*((double)RADIUS_REP - 1e-6);
            double loss_cd_hand = ((double)s0 + (double)s1) / (double)(B*NH);
            double loss_cd_obj  = ((double)s2 + (double)s3) / (NOd * valid);
            double loss_rep     = repx / (NOd * NOd * valid);
            double loss_pen     = (double)s5 / (NOd * valid);
            double loss_pose    = (double)s8 / valid;
            double loss_qpos    = (double)s7 / (double)(B*DQ);
            double loss_contact = (double)s6 / (double)(B*NH);
            double total = 5.0*loss_cd_hand + 5.0*loss_cd_obj + 2.0*loss_pose
                         + 1.0*loss_qpos + 2.0*loss_contact
                         + 0.5*loss_rep + 0.5*loss_pen;
            out[0] = (float)total;
        }
    }
}

extern "C" void kernel_launch(void* const* d_in, const int* in_sizes, int n_in,
                              void* d_out, int out_size, void* d_ws, size_t ws_size,
                              hipStream_t stream) {
    const float* pred_hand   = (const float*)d_in[0];
    const float* pred_obj    = (const float*)d_in[1];
    const float* pred_pose   = (const float*)d_in[2];
    const float* pred_qpos   = (const float*)d_in[3];
    const float* logits      = (const float*)d_in[4];
    const float* gt_hand     = (const float*)d_in[5];
    const float* gt_obj      = (const float*)d_in[6];
    const float* gt_pose     = (const float*)d_in[7];
    const float* gt_qpos     = (const float*)d_in[8];
    const float* gt_contact  = (const float*)d_in[9];
    const float* has_contact = (const float*)d_in[10];

    float* ws = (float*)d_ws;

    hipMemsetAsync(ws, 0, WS_SCAL * sizeof(float), stream);    // 64 B only

    loss_kernel<<<515, 256, 0, stream>>>(pred_hand, pred_obj, gt_hand, gt_obj,
                                         has_contact, logits, gt_contact,
                                         pred_qpos, gt_qpos, pred_pose, gt_pose,
                                         ws, (float*)d_out);
}